// Round 6
// baseline (86.976 us; speedup 1.0000x reference)
//
#include <hip/hip_runtime.h>
#include <hip/hip_bf16.h>

// LocallyConnected2d: B=16, C=32, O=32, H=W=64, K=3x3, pad=1, stride=1.
// out[b,o,h,w] = sum_{c,k} x[b,c,h+dh,w+dw] * weight[o,c,h,w,k]
//
// R6: kill the DS pipe (bperms were ~30us of serialized LDS time machine-wide;
// DS op ~11x a VALU op in per-CU throughput).
//  - x taps: 9 direct coalesced loads per (c,b), addressed as SGPR row base
//    (readfirstlane-forced uniform) + 3 precomputed VGPR column offsets ->
//    zero per-load VALU address math (what sank R2).
//  - weights: SGPR base + w*9 VGPR offset, same saddr trick.
//  - custom zero-fill kernel instead of hipMemsetAsync (rocclr fill showed
//    85us in rocprof for 8.4MB).
//  - grid/block shape as R5 (2048 blocks, 4-way c-split, atomics).

#define CIN  32
#define OCH  32
#define HH   64
#define WW   64
#define HW   (HH * WW)       // 4096
#define XB   (CIN * HW)      // per-batch x floats
#define BB   8               // batches per thread
#define OO   2               // output channels per thread
#define CC   8               // input channels per block (c-split 4)

typedef float f32x4 __attribute__((ext_vector_type(4), aligned(4)));

__global__ __launch_bounds__(256)
void zero_out_kernel(float* __restrict__ out, int n4) {
    int i = blockIdx.x * 256 + threadIdx.x;
    if (i < n4) ((f32x4*)out)[i] = (f32x4){0.f, 0.f, 0.f, 0.f};
}

__global__ __launch_bounds__(256)
void lc2d_kernel(const float* __restrict__ x,
                 const float* __restrict__ wt,
                 float* __restrict__ out) {
    const int w  = threadIdx.x;                 // lane == w
    const int h  = blockIdx.x * 4 + threadIdx.y;
    const int o0 = blockIdx.y * OO;
    const int bz = blockIdx.z & 1;              // batch half
    const int cg = blockIdx.z >> 1;             // c quarter
    const int b0 = bz * BB;
    const int c0 = cg * CC;

    // edge masks (folded into weights); clamped indices keep loads in-bounds
    const float mt = (h > 0)      ? 1.f : 0.f;
    const float mb = (h < HH - 1) ? 1.f : 0.f;
    const float ml = (w > 0)      ? 1.f : 0.f;
    const float mr = (w < WW - 1) ? 1.f : 0.f;
    const float mtml = mt * ml, mtmr = mt * mr, mbml = mb * ml, mbmr = mb * mr;
    const int iht = (h > 0)      ? h - 1 : 0;
    const int ihb = (h < HH - 1) ? h + 1 : HH - 1;

    // per-lane column offsets (VGPR, computed once)
    const int cl = (w > 0)      ? w - 1 : 0;
    const int cm = w;
    const int cr = (w < WW - 1) ? w + 1 : WW - 1;

    // wave-uniform row offsets, forced into SGPRs (wave == one ty row since
    // blockDim.x == 64, so readfirstlane is this wave's own h)
    const int rofT = __builtin_amdgcn_readfirstlane(iht * WW);
    const int rofM = __builtin_amdgcn_readfirstlane(h * WW);
    const int rofB = __builtin_amdgcn_readfirstlane(ihb * WW);
    const int wrow = __builtin_amdgcn_readfirstlane(h * WW * 9);  // weight row base (floats)
    const int wv   = w * 9;                                       // weight col offset (VGPR)

    float acc[OO * BB];
#pragma unroll
    for (int i = 0; i < OO * BB; ++i) acc[i] = 0.f;

    for (int c = 0; c < CC; ++c) {
        const int cc = c0 + c;
        // weight bases: all-scalar math (fits int32: max ~37.7M floats)
        const int wbA = (o0 * CIN + cc) * (HW * 9) + wrow;
        const int wbB = wbA + CIN * (HW * 9);

        f32x4 a03 = *(const f32x4*)(wt + wbA + wv);
        f32x4 a47 = *(const f32x4*)(wt + wbA + wv + 4);
        float a8  = wt[wbA + wv + 8];
        f32x4 b03 = *(const f32x4*)(wt + wbB + wv);
        f32x4 b47 = *(const f32x4*)(wt + wbB + wv + 4);
        float b8  = wt[wbB + wv + 8];

        const float wa0 = a03.x * mtml, wa1 = a03.y * mt, wa2 = a03.z * mtmr;
        const float wa3 = a03.w * ml,   wa4 = a47.x,      wa5 = a47.y * mr;
        const float wa6 = a47.z * mbml, wa7 = a47.w * mb, wa8 = a8 * mbmr;
        const float wb0 = b03.x * mtml, wb1 = b03.y * mt, wb2 = b03.z * mtmr;
        const float wb3 = b03.w * ml,   wb4 = b47.x,      wb5 = b47.y * mr;
        const float wb6 = b47.z * mbml, wb7 = b47.w * mb, wb8 = b8 * mbmr;

        int xrow = (b0 * CIN + cc) * HW;   // scalar; advances by XB per b
#pragma unroll
        for (int b = 0; b < BB; ++b) {
            const float* pT = x + xrow + rofT;   // SGPR base + VGPR col -> saddr loads
            const float* pM = x + xrow + rofM;
            const float* pB = x + xrow + rofB;
            const float xtl = pT[cl], xtm = pT[cm], xtr = pT[cr];
            const float xml = pM[cl], xmm = pM[cm], xmr = pM[cr];
            const float xbl = pB[cl], xbm = pB[cm], xbr = pB[cr];

            float a = acc[b];
            a = fmaf(xtl, wa0, a); a = fmaf(xtm, wa1, a); a = fmaf(xtr, wa2, a);
            a = fmaf(xml, wa3, a); a = fmaf(xmm, wa4, a); a = fmaf(xmr, wa5, a);
            a = fmaf(xbl, wa6, a); a = fmaf(xbm, wa7, a); a = fmaf(xbr, wa8, a);
            acc[b] = a;

            float q = acc[BB + b];
            q = fmaf(xtl, wb0, q); q = fmaf(xtm, wb1, q); q = fmaf(xtr, wb2, q);
            q = fmaf(xml, wb3, q); q = fmaf(xmm, wb4, q); q = fmaf(xmr, wb5, q);
            q = fmaf(xbl, wb6, q); q = fmaf(xbm, wb7, q); q = fmaf(xbr, wb8, q);
            acc[BB + b] = q;

            xrow += XB;
        }
    }

#pragma unroll
    for (int b = 0; b < BB; ++b) {
#pragma unroll
        for (int oo = 0; oo < OO; ++oo) {
            atomicAdd(out + (((size_t)(b0 + b) * OCH + (o0 + oo)) * HH + h) * WW + w,
                      acc[oo * BB + b]);
        }
    }
}

extern "C" void kernel_launch(void* const* d_in, const int* in_sizes, int n_in,
                              void* d_out, int out_size, void* d_ws, size_t ws_size,
                              hipStream_t stream) {
    const float* x  = (const float*)d_in[0];
    const float* wt = (const float*)d_in[1];
    float* out = (float*)d_out;

    const int n4 = out_size / 4;   // 524288 float4s
    zero_out_kernel<<<(n4 + 255) / 256, 256, 0, stream>>>(out, n4);

    dim3 block(64, 4);
    dim3 grid(HH / 4, OCH / OO, 8);   // 16 x 16 x (2 batch-halves * 4 c-quarters)
    lc2d_kernel<<<grid, block, 0, stream>>>(x, wt, out);
}

// Round 7
// 71.820 us; speedup vs baseline: 1.2110x; 1.2110x over previous
//
#include <hip/hip_runtime.h>
#include <hip/hip_bf16.h>

// LocallyConnected2d: B=16, C=32, O=32, H=W=64, K=3x3, pad=1, stride=1.
// out[b,o,h,w] = sum_{c,k} x[b,c,h+dh,w+dw] * weight[o,c,h,w,k]
//
// R7: TA-line-bound fix. Model: TA ~1 line-touch/cyc/CU; R5/R6's stride-36B
// weight loads cost ~69us of line-touches alone.
//  - weights: stage each contiguous 2304B (o,c,h)-row into LDS LINEARLY via
//    global_load_lds (16 lines/instr, every line touched once), then per-lane
//    ds_read of 9 floats (stride-9 dwords = conflict-free). Waves use private
//    LDS slots -> no barriers.
//  - x: pre-pass builds padded bf16 tap-windows XW[b][c][66][64] (ushort4 =
//    {x[w-1],x[w],x[w+1]}, zero pad rows/cols) in d_ws -> 3 aligned dwordx2
//    loads per (c,b), no masks/clamps in main loop. Fallback if ws too small.
//  - OO=4, BB=8, CC=8: grid 1024 blocks; LDS 36.9KB -> 4 blocks/CU.

#define CIN  32
#define OCH  32
#define HH   64
#define WW   64
#define HW   4096
#define BB   8     // batches per thread (batch-split 2)
#define OO   4     // output channels per thread
#define CC   8     // input channels per block (c-split 4)
#define XWR  66    // padded rows in XW

typedef float f32x4 __attribute__((ext_vector_type(4), aligned(16)));
typedef unsigned int u32x2 __attribute__((ext_vector_type(2), aligned(8)));

typedef const __attribute__((address_space(1))) unsigned int* gptr1_t;
typedef __attribute__((address_space(3))) unsigned int* lptr3_t;

__device__ __forceinline__ void stage16(const void* g, void* l) {
    __builtin_amdgcn_global_load_lds((gptr1_t)(unsigned long long)g,
                                     (lptr3_t)(unsigned int)(unsigned long long)l,
                                     16, 0, 0);
}
__device__ __forceinline__ void stage4(const void* g, void* l) {
    __builtin_amdgcn_global_load_lds((gptr1_t)(unsigned long long)g,
                                     (lptr3_t)(unsigned int)(unsigned long long)l,
                                     4, 0, 0);
}

__device__ __forceinline__ unsigned short f2bf(float f) {
    unsigned u = __float_as_uint(f);
    u += 0x7fffu + ((u >> 16) & 1u);
    return (unsigned short)(u >> 16);
}
__device__ __forceinline__ float bf_lo(unsigned v) { return __uint_as_float(v << 16); }
__device__ __forceinline__ float bf_hi(unsigned v) { return __uint_as_float(v & 0xffff0000u); }

__global__ __launch_bounds__(256)
void zero_out_kernel(float* __restrict__ out, int n4) {
    int i = blockIdx.x * 256 + threadIdx.x;
    if (i < n4) ((f32x4*)out)[i] = (f32x4){0.f, 0.f, 0.f, 0.f};
}

// Build XW[b][c][66][64] : ushort4{bf16 x[w-1], bf16 x[w], bf16 x[w+1], 0}
// rows 0 and 65 are zero (vertical pad); w edges zero-padded.
__global__ __launch_bounds__(256)
void xwin_kernel(const float* __restrict__ x, u32x2* __restrict__ xw) {
    int tid = blockIdx.x * 256 + threadIdx.x;
    const int total = 16 * CIN * XWR * 64;
    if (tid >= total) return;
    const int w  = tid & 63;
    const int r  = (tid >> 6) % XWR;
    const int bc = tid / (XWR * 64);
    const int h  = r - 1;
    float xl = 0.f, xm = 0.f, xr = 0.f;
    if (h >= 0 && h < HH) {
        const float* row = x + (size_t)bc * HW + (size_t)h * WW;
        xl = (w > 0)      ? row[w - 1] : 0.f;
        xm = row[w];
        xr = (w < WW - 1) ? row[w + 1] : 0.f;
    }
    u32x2 v;
    v.x = (unsigned)f2bf(xl) | ((unsigned)f2bf(xm) << 16);
    v.y = (unsigned)f2bf(xr);
    xw[tid] = v;
}

template<bool XWOK>
__global__ __launch_bounds__(256)
void lc2d_kernel(const float* __restrict__ x, const float* __restrict__ wt,
                 const u32x2* __restrict__ xw, float* __restrict__ out) {
    __shared__ float smem[4 * OO * 576];   // [ty][oo][576 floats] = 36864 B
    const int w  = threadIdx.x;                 // lane == w
    const int ty = threadIdx.y;
    const int h  = blockIdx.x * 4 + ty;
    const int o0 = blockIdx.y * OO;
    const int bz = blockIdx.z & 1;
    const int cg = blockIdx.z >> 1;
    const int b0 = bz * BB;
    const int c0 = cg * CC;

    // fallback-only edge handling
    const float mt = (h > 0) ? 1.f : 0.f, mb = (h < HH - 1) ? 1.f : 0.f;
    const float ml = (w > 0) ? 1.f : 0.f, mr = (w < WW - 1) ? 1.f : 0.f;
    const int iht = (h > 0) ? h - 1 : 0, ihb = (h < HH - 1) ? h + 1 : HH - 1;
    const int cl = (w > 0) ? w - 1 : 0, cr = (w < WW - 1) ? w + 1 : WW - 1;

    float acc[OO][BB];
#pragma unroll
    for (int oo = 0; oo < OO; ++oo)
#pragma unroll
        for (int b = 0; b < BB; ++b) acc[oo][b] = 0.f;

    float* ldsb = smem + (ty * OO) * 576;

    for (int c = 0; c < CC; ++c) {
        const int cc = c0 + c;

        // ---- stage 4 weight rows (2304B each, contiguous) linearly into LDS
#pragma unroll
        for (int oo = 0; oo < OO; ++oo) {
            const char* src = (const char*)wt
                + ((size_t)(o0 + oo) * CIN + cc) * ((size_t)HW * 36)
                + (size_t)h * 2304;
            float* lb = ldsb + oo * 576;
            stage16(src + (size_t)w * 16, lb);
            stage16(src + 1024 + (size_t)w * 16, lb + 256);
            stage4 (src + 2048 + (size_t)w * 4,  lb + 512);
        }
        __builtin_amdgcn_s_waitcnt(0);

        // ---- per-lane weights from LDS (stride-9 dwords: conflict-free)
        float wk[OO][9];
#pragma unroll
        for (int oo = 0; oo < OO; ++oo) {
            const float* wp = ldsb + oo * 576 + w * 9;
#pragma unroll
            for (int k = 0; k < 9; ++k) wk[oo][k] = wp[k];
        }
        if (!XWOK) {
            // fold edge masks (padded-x path needs none)
#pragma unroll
            for (int oo = 0; oo < OO; ++oo) {
                wk[oo][0] *= mt * ml; wk[oo][1] *= mt; wk[oo][2] *= mt * mr;
                wk[oo][3] *= ml;                        wk[oo][5] *= mr;
                wk[oo][6] *= mb * ml; wk[oo][7] *= mb; wk[oo][8] *= mb * mr;
            }
        }

        // ---- batch loop
        size_t xwi = ((size_t)b0 * CIN + cc) * (XWR * 64) + (size_t)h * 64 + w;
#pragma unroll
        for (int b = 0; b < BB; ++b) {
            float t0, t1, t2, t3, t4, t5, t6, t7, t8;
            if (XWOK) {
                const u32x2 r0 = xw[xwi];
                const u32x2 r1 = xw[xwi + 64];
                const u32x2 r2 = xw[xwi + 128];
                t0 = bf_lo(r0.x); t1 = bf_hi(r0.x); t2 = bf_lo(r0.y);
                t3 = bf_lo(r1.x); t4 = bf_hi(r1.x); t5 = bf_lo(r1.y);
                t6 = bf_lo(r2.x); t7 = bf_hi(r2.x); t8 = bf_lo(r2.y);
                xwi += (size_t)CIN * XWR * 64;
            } else {
                const float* xp = x + ((size_t)(b0 + b) * CIN + cc) * HW;
                const float* r0 = xp + iht * WW;
                const float* r1 = xp + h * WW;
                const float* r2 = xp + ihb * WW;
                t0 = r0[cl]; t1 = r0[w]; t2 = r0[cr];
                t3 = r1[cl]; t4 = r1[w]; t5 = r1[cr];
                t6 = r2[cl]; t7 = r2[w]; t8 = r2[cr];
            }
#pragma unroll
            for (int oo = 0; oo < OO; ++oo) {
                float a = acc[oo][b];
                a = fmaf(t0, wk[oo][0], a); a = fmaf(t1, wk[oo][1], a);
                a = fmaf(t2, wk[oo][2], a); a = fmaf(t3, wk[oo][3], a);
                a = fmaf(t4, wk[oo][4], a); a = fmaf(t5, wk[oo][5], a);
                a = fmaf(t6, wk[oo][6], a); a = fmaf(t7, wk[oo][7], a);
                a = fmaf(t8, wk[oo][8], a);
                acc[oo][b] = a;
            }
        }
    }

#pragma unroll
    for (int b = 0; b < BB; ++b)
#pragma unroll
        for (int oo = 0; oo < OO; ++oo)
            atomicAdd(out + (((size_t)(b0 + b) * OCH + (o0 + oo)) * HH + h) * WW + w,
                      acc[oo][b]);
}

extern "C" void kernel_launch(void* const* d_in, const int* in_sizes, int n_in,
                              void* d_out, int out_size, void* d_ws, size_t ws_size,
                              hipStream_t stream) {
    const float* x  = (const float*)d_in[0];
    const float* wt = (const float*)d_in[1];
    float* out = (float*)d_out;

    const int n4 = out_size / 4;
    zero_out_kernel<<<(n4 + 255) / 256, 256, 0, stream>>>(out, n4);

    const size_t ws_need = (size_t)16 * CIN * XWR * 64 * 8;   // 17.3 MB
    dim3 block(64, 4);
    dim3 grid(HH / 4, OCH / OO, 8);   // 16 x 8 x (2 bz * 4 cg) = 1024 blocks

    if (ws_size >= ws_need) {
        u32x2* xw = (u32x2*)d_ws;
        const int total = 16 * CIN * XWR * 64;
        xwin_kernel<<<(total + 255) / 256, 256, 0, stream>>>(x, xw);
        lc2d_kernel<true><<<grid, block, 0, stream>>>(x, wt, xw, out);
    } else {
        lc2d_kernel<false><<<grid, block, 0, stream>>>(x, wt, (const u32x2*)d_ws, out);
    }
}